// Round 1
// baseline (2214.496 us; speedup 1.0000x reference)
//
#include <hip/hip_runtime.h>
#include <math.h>

#define N_MEMBERS 2
#define N_NODES   65536
#define N_EDGES   1048576
#define N_LAYERS  12
#define D         64
#define OFF_STRIDE (N_NODES + 1)
#define NODE_MASK (N_NODES - 1)

// ---------- preprocessing ----------

__global__ __launch_bounds__(256) void count_deg_k(const int* __restrict__ ei,
                                                   int* __restrict__ deg) {
    int e = blockIdx.x * 256 + threadIdx.x;
    int m = blockIdx.y;
    int dst = ei[(size_t)(m * 2 + 1) * N_EDGES + e] & NODE_MASK;
    atomicAdd(&deg[m * N_NODES + dst], 1);
}

__global__ __launch_bounds__(256) void dinv_k(const int* __restrict__ deg,
                                              float* __restrict__ dinv) {
    int i = blockIdx.x * 256 + threadIdx.x;   // over 2*N_NODES
    dinv[i] = 1.0f / sqrtf((float)deg[i] + 1.0f);
}

// one block (1024 thr) per member: exclusive scan of deg[65536] -> off
__global__ __launch_bounds__(1024) void scan_k(const int* __restrict__ deg,
                                               int* __restrict__ off) {
    int m = blockIdx.x;
    const int* d = deg + m * N_NODES;
    int* o = off + m * OFF_STRIDE;
    __shared__ int part[1024];
    int t = threadIdx.x;
    int base = t * 64;
    int s = 0;
    for (int i = 0; i < 64; i++) s += d[base + i];
    part[t] = s;
    __syncthreads();
    for (int ofs = 1; ofs < 1024; ofs <<= 1) {
        int v = part[t];
        int add = (t >= ofs) ? part[t - ofs] : 0;
        __syncthreads();
        part[t] = v + add;
        __syncthreads();
    }
    int run = (t == 0) ? 0 : part[t - 1];
    for (int i = 0; i < 64; i++) { o[base + i] = run; run += d[base + i]; }
    if (t == 1023) o[N_NODES] = run;
}

__global__ __launch_bounds__(256) void fill_k(const int* __restrict__ ei,
                                              const int* __restrict__ off,
                                              int* __restrict__ cursor,
                                              const float* __restrict__ dinv,
                                              int* __restrict__ csr_src,
                                              float* __restrict__ csr_norm) {
    int e = blockIdx.x * 256 + threadIdx.x;
    int m = blockIdx.y;
    int src = ei[(size_t)(m * 2 + 0) * N_EDGES + e] & NODE_MASK;
    int dst = ei[(size_t)(m * 2 + 1) * N_EDGES + e] & NODE_MASK;
    int pos = off[m * OFF_STRIDE + dst] + atomicAdd(&cursor[m * N_NODES + dst], 1);
    csr_src[(size_t)m * N_EDGES + pos] = src;
    csr_norm[(size_t)m * N_EDGES + pos] =
        dinv[m * N_NODES + src] * dinv[m * N_NODES + dst];
}

// ---------- per-layer: hw = h @ W[m][layer] (no bias) ----------
// lane = output column; W column cached in 64 VGPRs; rows broadcast via
// wave-uniform float4 loads -> inner loop is pure v_fma_f32.
__global__ __launch_bounds__(256) void gemm_k(const float* __restrict__ h,
                                              const float* __restrict__ Wall,
                                              float* __restrict__ hw, int layer) {
    int m = blockIdx.y;
    const float* Wg = Wall + (size_t)(m * N_LAYERS + layer) * D * D;
    __shared__ float Wsh[D * D];
    {
        const float4* s4 = (const float4*)Wg;
        float4* d4 = (float4*)Wsh;
        for (int i = threadIdx.x; i < D * D / 4; i += 256) d4[i] = s4[i];
    }
    __syncthreads();
    int lane = threadIdx.x & 63;
    int wav  = threadIdx.x >> 6;
    float wreg[D];
    #pragma unroll
    for (int k = 0; k < D; k++) wreg[k] = Wsh[k * D + lane];

    const int NPW = 32;                       // nodes per wave
    int n0 = (blockIdx.x * 4 + wav) * NPW;
    const float* hm = h  + (size_t)m * N_NODES * D;
    float*       om = hw + (size_t)m * N_NODES * D;
    for (int n = n0; n < n0 + NPW; n++) {
        const float4* row = (const float4*)(hm + (size_t)n * D);
        float acc = 0.0f;
        #pragma unroll
        for (int k4 = 0; k4 < D / 4; k4++) {
            float4 a = row[k4];
            acc = fmaf(a.x, wreg[4 * k4 + 0], acc);
            acc = fmaf(a.y, wreg[4 * k4 + 1], acc);
            acc = fmaf(a.z, wreg[4 * k4 + 2], acc);
            acc = fmaf(a.w, wreg[4 * k4 + 3], acc);
        }
        om[(size_t)n * D + lane] = acc;
    }
}

// ---------- per-layer: out = sum_e norm*hw[src] + dinv^2*hw[n] + b [; relu] ----
// one wave per node, lane = feature dim, coalesced 256B gathers.
__global__ __launch_bounds__(256) void aggregate_k(const float* __restrict__ hw,
                                                   float* __restrict__ out,
                                                   const int* __restrict__ off,
                                                   const int* __restrict__ csr_src,
                                                   const float* __restrict__ csr_norm,
                                                   const float* __restrict__ dinv,
                                                   const float* __restrict__ ball,
                                                   int layer, int relu) {
    int m = blockIdx.y;
    int n = blockIdx.x * 4 + (threadIdx.x >> 6);
    int lane = threadIdx.x & 63;
    const float* hm = hw + (size_t)m * N_NODES * D;
    const int*   ob = off + m * OFF_STRIDE;
    const int*   sb = csr_src  + (size_t)m * N_EDGES;
    const float* wb = csr_norm + (size_t)m * N_EDGES;

    float dv  = dinv[m * N_NODES + n];
    float acc = dv * dv * hm[(size_t)n * D + lane];

    int e0 = ob[n], e1 = ob[n + 1];
    int e = e0;
    for (; e + 4 <= e1; e += 4) {
        int   s0 = sb[e],   s1 = sb[e+1], s2 = sb[e+2], s3 = sb[e+3];
        float w0 = wb[e],   w1 = wb[e+1], w2 = wb[e+2], w3 = wb[e+3];
        float g0 = hm[(size_t)s0 * D + lane];
        float g1 = hm[(size_t)s1 * D + lane];
        float g2 = hm[(size_t)s2 * D + lane];
        float g3 = hm[(size_t)s3 * D + lane];
        acc = fmaf(w0, g0, acc);
        acc = fmaf(w1, g1, acc);
        acc = fmaf(w2, g2, acc);
        acc = fmaf(w3, g3, acc);
    }
    for (; e < e1; e++) acc = fmaf(wb[e], hm[(size_t)sb[e] * D + lane], acc);

    acc += ball[(size_t)(m * N_LAYERS + layer) * D + lane];
    if (relu) acc = fmaxf(acc, 0.0f);
    out[(size_t)m * N_NODES * D + (size_t)n * D + lane] = acc;
}

// ---------- host ----------

extern "C" void kernel_launch(void* const* d_in, const int* in_sizes, int n_in,
                              void* d_out, int out_size, void* d_ws, size_t ws_size,
                              hipStream_t stream) {
    (void)in_sizes; (void)n_in; (void)out_size; (void)ws_size;
    const float* x  = (const float*)d_in[0];
    const int*   ei = (const int*)d_in[1];      // harness delivers int32
    const float* W  = (const float*)d_in[2];
    const float* b  = (const float*)d_in[3];
    float* out = (float*)d_out;

    char* ws = (char*)d_ws;
    size_t o = 0;
    auto take = [&](size_t bytes) -> void* {
        void* p = ws + o;
        o = (o + bytes + 255) & ~(size_t)255;
        return p;
    };
    int*   deg      = (int*)  take((size_t)N_MEMBERS * N_NODES * 4);
    int*   cursor   = (int*)  take((size_t)N_MEMBERS * N_NODES * 4);
    float* dinv     = (float*)take((size_t)N_MEMBERS * N_NODES * 4);
    int*   off      = (int*)  take((size_t)N_MEMBERS * OFF_STRIDE * 4);
    int*   csr_src  = (int*)  take((size_t)N_MEMBERS * N_EDGES * 4);
    float* csr_norm = (float*)take((size_t)N_MEMBERS * N_EDGES * 4);
    float* tbuf     = (float*)take((size_t)N_MEMBERS * N_NODES * D * 4);
    float* hbuf     = (float*)take((size_t)N_MEMBERS * N_NODES * D * 4);

    // zero deg + cursor (adjacent, both 256-padded)
    hipMemsetAsync(deg, 0, 2 * (size_t)N_MEMBERS * N_NODES * 4, stream);

    count_deg_k<<<dim3(N_EDGES / 256, N_MEMBERS), 256, 0, stream>>>(ei, deg);
    dinv_k<<<dim3((N_MEMBERS * N_NODES) / 256), 256, 0, stream>>>(deg, dinv);
    scan_k<<<dim3(N_MEMBERS), 1024, 0, stream>>>(deg, off);
    fill_k<<<dim3(N_EDGES / 256, N_MEMBERS), 256, 0, stream>>>(ei, off, cursor, dinv,
                                                               csr_src, csr_norm);

    const float* hin = x;
    for (int j = 0; j < N_LAYERS; j++) {
        gemm_k<<<dim3(N_NODES / (4 * 32), N_MEMBERS), 256, 0, stream>>>(hin, W, tbuf, j);
        float* dst = (j == N_LAYERS - 1) ? out : hbuf;
        aggregate_k<<<dim3(N_NODES / 4, N_MEMBERS), 256, 0, stream>>>(
            tbuf, dst, off, csr_src, csr_norm, dinv, b, j, (j < N_LAYERS - 1) ? 1 : 0);
        hin = hbuf;
    }
}